// Round 5
// baseline (147.350 us; speedup 1.0000x reference)
//
#include <hip/hip_runtime.h>
#include <math.h>

// CIoU loss, fp32, N = 4194304.
// Round 5 (= round 4 resubmit; bench never ran). Latency-bound fix:
// pin the 16-load cluster with __builtin_amdgcn_sched_barrier(0) so all
// global_load_dwordx4 issue before any compute (progressive vmcnt waits give
// per-element overlap). Single-atan identity retained. Two-kernel
// deterministic reduction unchanged.

#define EPS 1e-6f
#define NBLOCKS 2048
#define NTHREADS 256
#define PER_THREAD 8

__device__ __forceinline__ float ciou_loss(float4 p, float4 t)
{
    const float inv_pi2_4 = 4.0f / (float)(M_PI * M_PI);

    float pw = p.z - p.x, ph = p.w - p.y;
    float tw = t.z - t.x, th = t.w - t.y;
    float area_p = pw * ph;
    float area_t = tw * th;

    float ix = fminf(p.z, t.z) - fmaxf(p.x, t.x);
    float iy = fminf(p.w, t.w) - fmaxf(p.y, t.y);
    ix = fmaxf(ix, 0.0f);
    iy = fmaxf(iy, 0.0f);
    float inter = ix * iy;
    float uni = area_p + area_t - inter;
    float iou = inter / fmaxf(uni, EPS);

    float dcx = 0.5f * ((p.x + p.z) - (t.x + t.z));
    float dcy = 0.5f * ((p.y + p.w) - (t.y + t.w));
    float center_d = dcx * dcx + dcy * dcy;

    float ex = fmaxf(p.z, t.z) - fminf(p.x, t.x);
    float ey = fmaxf(p.w, t.w) - fminf(p.y, t.y);
    float diag_d = ex * ex + ey * ey;

    // atan(tw/th) - atan(pw/ph) == atan((tw*ph - pw*th) / (th*ph + tw*pw))
    // valid: both ratios > 0 (wh > 1e-3 by construction), so den > 0.
    float num = tw * ph - pw * th;
    float den = th * ph + tw * pw;
    float da = atanf(num / den);
    float v = inv_pi2_4 * da * da;
    float alpha = v / (1.0f - iou + v + EPS);

    float ciou = iou - center_d / fmaxf(diag_d, EPS) + alpha * v;
    return 1.0f - ciou;
}

__global__ __launch_bounds__(NTHREADS) void ciou_partial_kernel(
    const float4* __restrict__ pred,
    const float4* __restrict__ tgt,
    float* __restrict__ partials,
    int n)
{
    float acc;
    const int tid = blockIdx.x * NTHREADS + threadIdx.x;
    const int stride = NBLOCKS * NTHREADS;

    if (n == stride * PER_THREAD) {
        // All 16 loads issued before ANY compute. sched_barrier(0) forbids the
        // scheduler from sinking loads past it; compiler then emits progressive
        // vmcnt(N) waits so elem-k compute overlaps elems k+1.. loads in flight.
        float4 p[PER_THREAD], t[PER_THREAD];
        #pragma unroll
        for (int k = 0; k < PER_THREAD; ++k) {
            int i = tid + k * stride;
            p[k] = pred[i];
            t[k] = tgt[i];
        }
        __builtin_amdgcn_sched_barrier(0);
        float acc0 = 0.0f, acc1 = 0.0f;
        #pragma unroll
        for (int k = 0; k < PER_THREAD; ++k) {
            float l = ciou_loss(p[k], t[k]);
            if (k & 1) acc1 += l; else acc0 += l;
        }
        acc = acc0 + acc1;
    } else {
        acc = 0.0f;
        for (int i = tid; i < n; i += stride)
            acc += ciou_loss(pred[i], tgt[i]);
    }

    // wave-64 reduce
    #pragma unroll
    for (int off = 32; off > 0; off >>= 1)
        acc += __shfl_down(acc, off, 64);

    __shared__ float wsum[NTHREADS / 64];
    int lane = threadIdx.x & 63;
    int wid  = threadIdx.x >> 6;
    if (lane == 0) wsum[wid] = acc;
    __syncthreads();
    if (threadIdx.x == 0) {
        float b = wsum[0];
        #pragma unroll
        for (int w = 1; w < NTHREADS / 64; ++w) b += wsum[w];
        partials[blockIdx.x] = b;
    }
}

__global__ __launch_bounds__(NTHREADS) void ciou_finalize_kernel(
    const float* __restrict__ partials, float* __restrict__ out, int nblocks, float inv_n)
{
    double acc = 0.0;
    for (int i = threadIdx.x; i < nblocks; i += NTHREADS)
        acc += (double)partials[i];

    #pragma unroll
    for (int off = 32; off > 0; off >>= 1)
        acc += __shfl_down(acc, off, 64);

    __shared__ double wsum[NTHREADS / 64];
    int lane = threadIdx.x & 63;
    int wid  = threadIdx.x >> 6;
    if (lane == 0) wsum[wid] = acc;
    __syncthreads();
    if (threadIdx.x == 0) {
        double b = wsum[0];
        #pragma unroll
        for (int w = 1; w < NTHREADS / 64; ++w) b += wsum[w];
        out[0] = (float)(b * (double)inv_n);
    }
}

extern "C" void kernel_launch(void* const* d_in, const int* in_sizes, int n_in,
                              void* d_out, int out_size, void* d_ws, size_t ws_size,
                              hipStream_t stream)
{
    const float4* pred = (const float4*)d_in[0];
    const float4* tgt  = (const float4*)d_in[1];
    int n = in_sizes[0] / 4;

    float* partials = (float*)d_ws;
    float* out = (float*)d_out;

    ciou_partial_kernel<<<NBLOCKS, NTHREADS, 0, stream>>>(pred, tgt, partials, n);
    ciou_finalize_kernel<<<1, NTHREADS, 0, stream>>>(partials, out, NBLOCKS, 1.0f / (float)n);
}